// Round 4
// baseline (691.182 us; speedup 1.0000x reference)
//
#include <hip/hip_runtime.h>
#include <hip/hip_bf16.h>
#include <stdint.h>

typedef __attribute__((ext_vector_type(4))) short short4v;
typedef __attribute__((ext_vector_type(8))) short short8v;
typedef __attribute__((ext_vector_type(4))) float float4v;

#define NN 8192
#define FIN 256
#define FOUT 256

__device__ __forceinline__ short f2bf(float f) {
    unsigned u = __float_as_uint(f);
    unsigned r = u + 0x7fffu + ((u >> 16) & 1u);   // RNE
    return (short)(r >> 16);
}

// W [256][256] fp32 -> WT [n][k] bf16
__global__ __launch_bounds__(256) void k_wt(const float* __restrict__ W, short* __restrict__ WT) {
    int k = blockIdx.x, n = threadIdx.x;
    WT[n * 256 + k] = f2bf(W[k * 256 + n]);
}

// Wh = h @ W  (M=8192, N=256, K=256), bf16 MFMA, 64x64 tile, BK=32
__global__ __launch_bounds__(256) void k_gemm1(const float* __restrict__ h, const short* __restrict__ WT,
                                               float* __restrict__ Wh) {
    __shared__ short sA[64 * 40];
    __shared__ short sB[64 * 40];
    int bm = blockIdx.x;   // 0..127
    int bn = blockIdx.y;   // 0..3
    int t  = threadIdx.x;
    int w = t >> 6, lane = t & 63, quad = lane >> 4, l16 = lane & 15;

    float4v acc[4];
#pragma unroll
    for (int c = 0; c < 4; c++)
#pragma unroll
        for (int j = 0; j < 4; j++) acc[c][j] = 0.f;

    int r  = t >> 2;            // 0..63
    int ko = (t & 3) * 8;       // 0,8,16,24

    for (int k0 = 0; k0 < 256; k0 += 32) {
        const float4v* src = (const float4v*)&h[(size_t)(64 * bm + r) * 256 + k0 + ko];
        float4v v0 = src[0], v1 = src[1];
        short8v pk;
        pk[0] = f2bf(v0[0]); pk[1] = f2bf(v0[1]); pk[2] = f2bf(v0[2]); pk[3] = f2bf(v0[3]);
        pk[4] = f2bf(v1[0]); pk[5] = f2bf(v1[1]); pk[6] = f2bf(v1[2]); pk[7] = f2bf(v1[3]);
        *(short8v*)&sA[r * 40 + ko] = pk;
        short8v bv = *(const short8v*)&WT[(size_t)(64 * bn + r) * 256 + k0 + ko];
        *(short8v*)&sB[r * 40 + ko] = bv;
        __syncthreads();

        short8v af = *(const short8v*)&sA[(16 * w + l16) * 40 + quad * 8];
#pragma unroll
        for (int c = 0; c < 4; c++) {
            short8v bf = *(const short8v*)&sB[(16 * c + l16) * 40 + quad * 8];
            acc[c] = __builtin_amdgcn_mfma_f32_16x16x32_bf16(af, bf, acc[c], 0, 0, 0);
        }
        __syncthreads();
    }
#pragma unroll
    for (int c = 0; c < 4; c++)
#pragma unroll
        for (int j = 0; j < 4; j++) {
            int row = 64 * bm + 16 * w + quad * 4 + j;
            int col = 64 * bn + 16 * c + l16;
            Wh[(size_t)row * 256 + col] = acc[c][j];
        }
}

// Wh1 = Wh@a1, Wh2 = Wh@a2, global max(Wh2) via encoded atomicMax. 4 rows/block (1/wave).
__global__ __launch_bounds__(256) void k_rowstats(const float* __restrict__ Wh, const float* __restrict__ a,
                                                  float* __restrict__ Wh1, float* __restrict__ Wh2,
                                                  unsigned* __restrict__ maxenc) {
    int w = threadIdx.x >> 6, lane = threadIdx.x & 63;
    int row = blockIdx.x * 4 + w;
    float s1 = 0.f, s2 = 0.f;
#pragma unroll
    for (int j = 0; j < 4; j++) {
        int c = lane + 64 * j;
        float v = Wh[(size_t)row * 256 + c];
        s1 += v * a[c];
        s2 += v * a[256 + c];
    }
#pragma unroll
    for (int off = 32; off; off >>= 1) {
        s1 += __shfl_down(s1, off);
        s2 += __shfl_down(s2, off);
    }
    if (lane == 0) {
        Wh1[row] = s1;
        Wh2[row] = s2;
        unsigned u = __float_as_uint(s2);
        unsigned key = (u & 0x80000000u) ? ~u : (u | 0x80000000u);
        atomicMax(maxenc, key);
    }
}

// WhT[n][k] bf16 from Wh[k][n] fp32, 64x64 LDS tile
__global__ __launch_bounds__(256) void k_transpose(const float* __restrict__ Wh, short* __restrict__ WhT) {
    __shared__ short sT[64 * 72];
    int bm = blockIdx.x, bn = blockIdx.y;
    int t = threadIdx.x;
#pragma unroll
    for (int i = 0; i < 4; i++) {
        int idx = i * 256 + t;
        int r = idx >> 4, c4 = (idx & 15) * 4;
        float4v v = *(const float4v*)&Wh[(size_t)(64 * bm + r) * 256 + 64 * bn + c4];
#pragma unroll
        for (int j = 0; j < 4; j++) sT[(c4 + j) * 72 + r] = f2bf(v[j]);
    }
    __syncthreads();
    int c = t >> 2, ro = (t & 3) * 16;
#pragma unroll
    for (int hh = 0; hh < 2; hh++) {
        short8v v = *(const short8v*)&sT[c * 72 + ro + 8 * hh];
        *(short8v*)&WhT[(size_t)(64 * bn + c) * 8192 + 64 * bm + ro + 8 * hh] = v;
    }
}

// Fused masked-softmax GEMM, K-split. Grid (128, S). Block: M=64 rows, K slice Ksub, N=256.
// 512 threads / 8 waves; wave tile 32x64 (acc[2][4]).
// T14 reg-staged pipeline, SPILL-FREE form: all pipeline state in NAMED scalars (no lambda,
// no address-taken arrays -> rule #20). Per stage:
//   issue adj/w2(k+1) + B(k+2) global loads        (>= 1 full stage of slack, counted waits)
//   ds_write B(k+1) regs -> sB[cur^1]              (compiler inserts counted vmcnt wait)
//   P-compute(k) -> sA
//   lgkmcnt(0); s_barrier                          (global loads stay in flight)
//   MFMA reads sA + sB[cur]; s_barrier
// Zero vmcnt(0) in the main loop. LDS 73KB -> 2 blocks/CU; (512,4): VGPR cap 128 (est ~115).
__global__ __launch_bounds__(512, 4) void k_gat(const float* __restrict__ adj, const short* __restrict__ WhT,
                                                const float* __restrict__ Wh1, const float* __restrict__ Wh2,
                                                const unsigned* __restrict__ maxenc,
                                                float* __restrict__ Cacc, float* __restrict__ Lacc,
                                                int Ksub) {
    __shared__ short sB[2][256 * 64]; // unpadded: row n = 64 shorts (128B), chunk-XOR swizzled
    __shared__ short sA[64 * 72];     // padded stride 72 shorts (144B = 9*16B -> conflict-free b128)
    int bm = blockIdx.x;              // 0..127 (64 rows each)
    int sidx = blockIdx.y;
    int kb = sidx * Ksub;
    int t = threadIdx.x;
    int lane = t & 63, quad = lane >> 4, l16 = lane & 15;
    int w = t >> 6;                   // 0..7
    int mr = (w >> 2) * 32;           // wave row offset: 0 or 32
    int cg = w & 3;                   // col-group 0..3 (64 cols each)

    // decode global max(Wh2)
    unsigned key = maxenc[0];
    unsigned u = (key & 0x80000000u) ? (key & 0x7fffffffu) : ~key;
    float maxw2 = __uint_as_float(u);

    // ---- P staging mapping: 8 threads per row
    int r  = t >> 3;          // staging row 0..63
    int kc = (t & 7) * 8;     // staging k offset 0..56
    float wh1r = Wh1[64 * bm + r];
    float sup = wh1r + maxw2;
    float ci = fmaxf(sup, 0.2f * sup);   // leaky_relu monotone => e_ij <= ci for all j

    const float* adj_row = &adj[(size_t)(64 * bm + r) * 8192 + kb];
    const float* w2base  = &Wh2[kb];

    // ---- B staging mapping: thread t owns row n = t>>1, half = t&1 (4 x b128 per stage)
    int nrow = t >> 1;
    int half = t & 1;
    const short* gB = &WhT[(size_t)nrow * 8192 + kb + half * 32];
    int nx = nrow & 7;
    // precomputed swizzled LDS write offsets (shorts)
    int sbw0 = nrow * 64 + (((half * 4 + 0) ^ nx)) * 8;
    int sbw1 = nrow * 64 + (((half * 4 + 1) ^ nx)) * 8;
    int sbw2 = nrow * 64 + (((half * 4 + 2) ^ nx)) * 8;
    int sbw3 = nrow * 64 + (((half * 4 + 3) ^ nx)) * 8;

    float4v acc[2][4];
#pragma unroll
    for (int rt = 0; rt < 2; rt++)
#pragma unroll
        for (int c = 0; c < 4; c++)
#pragma unroll
            for (int j = 0; j < 4; j++) acc[rt][c][j] = 0.f;
    float lsum = 0.f;

    // pipeline state: named scalars only
    short8v a0, a1, a2, a3;       // B ping
    short8v b0, b1, b2, b3;       // B pong
    float4v av0, av1, w20, w21;   // adj/w2 ping
    float4v cv0, cv1, x20, x21;   // adj/w2 pong

    // ---- prologue: adj/w2(0); B(0) -> write sB[0]; issue B(64)
    av0 = *(const float4v*)&adj_row[kc];
    av1 = *(const float4v*)&adj_row[kc + 4];
    w20 = *(const float4v*)&w2base[kc];
    w21 = *(const float4v*)&w2base[kc + 4];
    a0 = *(const short8v*)&gB[0];
    a1 = *(const short8v*)&gB[8];
    a2 = *(const short8v*)&gB[16];
    a3 = *(const short8v*)&gB[24];
    *(short8v*)&sB[0][sbw0] = a0;
    *(short8v*)&sB[0][sbw1] = a1;
    *(short8v*)&sB[0][sbw2] = a2;
    *(short8v*)&sB[0][sbw3] = a3;
    b0 = *(const short8v*)&gB[64];
    b1 = *(const short8v*)&gB[64 + 8];
    b2 = *(const short8v*)&gB[64 + 16];
    b3 = *(const short8v*)&gB[64 + 24];

// One pipeline stage. C0..C3 = B(k0+64) regs (write into sB[CUR^1]); N0..N3 receive B(k0+128).
// AV*/AW* = current adj/w2; NV*/NW* receive next.
#define STAGE(K0, CUR, C0, C1, C2, C3, N0, N1, N2, N3, AV0, AV1, AW0, AW1, NV0, NV1, NW0, NW1)   \
    {                                                                                            \
        int k1 = (K0) + 64, k2 = (K0) + 128;                                                     \
        if (k1 < Ksub) {                                                                         \
            NV0 = *(const float4v*)&adj_row[k1 + kc];                                            \
            NV1 = *(const float4v*)&adj_row[k1 + kc + 4];                                        \
            NW0 = *(const float4v*)&w2base[k1 + kc];                                             \
            NW1 = *(const float4v*)&w2base[k1 + kc + 4];                                         \
        }                                                                                        \
        if (k2 < Ksub) {                                                                         \
            N0 = *(const short8v*)&gB[k2];                                                       \
            N1 = *(const short8v*)&gB[k2 + 8];                                                   \
            N2 = *(const short8v*)&gB[k2 + 16];                                                  \
            N3 = *(const short8v*)&gB[k2 + 24];                                                  \
        }                                                                                        \
        if (k1 < Ksub) {                                                                         \
            *(short8v*)&sB[(CUR) ^ 1][sbw0] = C0;                                                \
            *(short8v*)&sB[(CUR) ^ 1][sbw1] = C1;                                                \
            *(short8v*)&sB[(CUR) ^ 1][sbw2] = C2;                                                \
            *(short8v*)&sB[(CUR) ^ 1][sbw3] = C3;                                                \
        }                                                                                        \
        short8v pk;                                                                              \
        _Pragma("unroll")                                                                        \
        for (int j = 0; j < 4; j++) {                                                            \
            float s = wh1r + AW0[j];                                                             \
            float f = fmaxf(s, 0.2f * s);                                                        \
            float p = __expf(f - ci);                                                            \
            p = (AV0[j] > 0.f) ? p : 0.f;                                                        \
            lsum += p;                                                                           \
            pk[j] = f2bf(p);                                                                     \
        }                                                                                        \
        _Pragma("unroll")                                                                        \
        for (int j = 0; j < 4; j++) {                                                            \
            float s = wh1r + AW1[j];                                                             \
            float f = fmaxf(s, 0.2f * s);                                                        \
            float p = __expf(f - ci);                                                            \
            p = (AV1[j] > 0.f) ? p : 0.f;                                                        \
            lsum += p;                                                                           \
            pk[4 + j] = f2bf(p);                                                                 \
        }                                                                                        \
        *(short8v*)&sA[r * 72 + kc] = pk;                                                        \
        asm volatile("s_waitcnt lgkmcnt(0)" ::: "memory");                                       \
        __builtin_amdgcn_s_barrier();                                                            \
        __builtin_amdgcn_s_setprio(1);                                                           \
        {                                                                                        \
            const short* sBc = &sB[(CUR)][0];                                                    \
            _Pragma("unroll")                                                                    \
            for (int kk = 0; kk < 2; kk++) {                                                     \
                short8v af0 = *(const short8v*)&sA[(mr + l16) * 72 + kk * 32 + quad * 8];        \
                short8v af1 = *(const short8v*)&sA[(mr + 16 + l16) * 72 + kk * 32 + quad * 8];   \
                _Pragma("unroll")                                                                \
                for (int c = 0; c < 4; c++) {                                                    \
                    int n = 64 * cg + 16 * c + l16;                                              \
                    int ch = (kk * 4 + quad) ^ (n & 7);                                          \
                    short8v bf = *(const short8v*)&sBc[n * 64 + ch * 8];                         \
                    acc[0][c] = __builtin_amdgcn_mfma_f32_16x16x32_bf16(af0, bf, acc[0][c], 0, 0, 0); \
                    acc[1][c] = __builtin_amdgcn_mfma_f32_16x16x32_bf16(af1, bf, acc[1][c], 0, 0, 0); \
                }                                                                                \
            }                                                                                    \
        }                                                                                        \
        __builtin_amdgcn_s_setprio(0);                                                           \
        __builtin_amdgcn_s_barrier();                                                            \
    }

    for (int k0 = 0; k0 < Ksub; k0 += 128) {
        STAGE(k0,      0, b0, b1, b2, b3, a0, a1, a2, a3, av0, av1, w20, w21, cv0, cv1, x20, x21)
        STAGE(k0 + 64, 1, a0, a1, a2, a3, b0, b1, b2, b3, cv0, cv1, x20, x21, av0, av1, w20, w21)
    }
#undef STAGE

    // reduce lsum across the 8 staging threads that share a row, then accumulate
#pragma unroll
    for (int off = 4; off; off >>= 1) lsum += __shfl_xor(lsum, off, 8);
    if ((t & 7) == 0) atomicAdd(&Lacc[64 * bm + r], lsum);

#pragma unroll
    for (int rt = 0; rt < 2; rt++)
#pragma unroll
        for (int c = 0; c < 4; c++)
#pragma unroll
            for (int j = 0; j < 4; j++) {
                int row = 64 * bm + mr + rt * 16 + quad * 4 + j;
                int col = 64 * cg + 16 * c + l16;
                atomicAdd(&Cacc[(size_t)row * 256 + col], acc[rt][c][j]);
            }
}

// out = elu( Cacc / Lacc )
__global__ __launch_bounds__(256) void k_final(const float* __restrict__ Cacc, const float* __restrict__ Lacc,
                                               float* __restrict__ out) {
    int idx = blockIdx.x * 256 + threadIdx.x;     // one float4 per thread; 2048 blocks
    int row = idx >> 6;
    int c4 = (idx & 63) * 4;
    float4v v = *(const float4v*)&Cacc[(size_t)row * 256 + c4];
    float inv = 1.0f / fmaxf(Lacc[row], 1e-30f);
    float4v o;
#pragma unroll
    for (int j = 0; j < 4; j++) {
        float x = v[j] * inv;
        o[j] = (x > 0.f) ? x : (__expf(x) - 1.f);
    }
    *(float4v*)&out[(size_t)row * 256 + c4] = o;
}

extern "C" void kernel_launch(void* const* d_in, const int* in_sizes, int n_in,
                              void* d_out, int out_size, void* d_ws, size_t ws_size,
                              hipStream_t stream) {
    const float* h   = (const float*)d_in[0];
    const float* adj = (const float*)d_in[1];
    const float* W   = (const float*)d_in[2];
    const float* a   = (const float*)d_in[3];
    float* out = (float*)d_out;

    const int S = 4;
    const int Ksub = NN / S;

    // ws layout (12.8 MB):
    //  [0, 8MB)      Wh (fp32)  — dead after k_rowstats/k_transpose, then ALIASED as Cacc
    //  [8MB, 12MB)   WhT (bf16)
    //  tail: WT 128KB | Wh1 32KB | Wh2 32KB | Lacc 32KB | maxenc 4B
    char* ws = (char*)d_ws;
    float*    Wh     = (float*)(ws);
    float*    Cacc   = (float*)(ws);                 // alias of Wh (stream-ordered safe)
    short*    WhT    = (short*)(ws + 8388608);
    char*     tail   = ws + 12582912;
    short*    WT     = (short*)(tail);
    float*    Wh1    = (float*)(tail + 131072);
    float*    Wh2    = (float*)(tail + 163840);
    float*    Lacc   = (float*)(tail + 196608);
    unsigned* maxenc = (unsigned*)(tail + 229376);

    hipMemsetAsync(maxenc, 0, sizeof(unsigned), stream);

    k_wt<<<256, 256, 0, stream>>>(W, WT);
    k_gemm1<<<dim3(128, 4), 256, 0, stream>>>(h, WT, Wh);
    k_rowstats<<<2048, 256, 0, stream>>>(Wh, a, Wh1, Wh2, maxenc);
    k_transpose<<<dim3(128, 4), 256, 0, stream>>>(Wh, WhT);
    // Wh is dead now; zero it for use as Cacc, zero Lacc
    hipMemsetAsync(Cacc, 0, (size_t)NN * 256 * sizeof(float), stream);
    hipMemsetAsync(Lacc, 0, (size_t)NN * sizeof(float), stream);
    k_gat<<<dim3(128, S), 512, 0, stream>>>(adj, WhT, Wh1, Wh2, maxenc, Cacc, Lacc, Ksub);
    k_final<<<2048, 256, 0, stream>>>(Cacc, Lacc, out);
}

// Round 5
// 568.456 us; speedup vs baseline: 1.2159x; 1.2159x over previous
//
#include <hip/hip_runtime.h>
#include <hip/hip_bf16.h>
#include <stdint.h>

typedef __attribute__((ext_vector_type(4))) short short4v;
typedef __attribute__((ext_vector_type(8))) short short8v;
typedef __attribute__((ext_vector_type(4))) float float4v;

#define NN 8192
#define FIN 256
#define FOUT 256

__device__ __forceinline__ short f2bf(float f) {
    unsigned u = __float_as_uint(f);
    unsigned r = u + 0x7fffu + ((u >> 16) & 1u);   // RNE
    return (short)(r >> 16);
}

// W [256][256] fp32 -> WT [n][k] bf16
__global__ __launch_bounds__(256) void k_wt(const float* __restrict__ W, short* __restrict__ WT) {
    int k = blockIdx.x, n = threadIdx.x;
    WT[n * 256 + k] = f2bf(W[k * 256 + n]);
}

// Wh = h @ W  (M=8192, N=256, K=256), bf16 MFMA, 64x64 tile, BK=32
__global__ __launch_bounds__(256) void k_gemm1(const float* __restrict__ h, const short* __restrict__ WT,
                                               float* __restrict__ Wh) {
    __shared__ short sA[64 * 40];
    __shared__ short sB[64 * 40];
    int bm = blockIdx.x;   // 0..127
    int bn = blockIdx.y;   // 0..3
    int t  = threadIdx.x;
    int w = t >> 6, lane = t & 63, quad = lane >> 4, l16 = lane & 15;

    float4v acc[4];
#pragma unroll
    for (int c = 0; c < 4; c++)
#pragma unroll
        for (int j = 0; j < 4; j++) acc[c][j] = 0.f;

    int r  = t >> 2;            // 0..63
    int ko = (t & 3) * 8;       // 0,8,16,24

    for (int k0 = 0; k0 < 256; k0 += 32) {
        const float4v* src = (const float4v*)&h[(size_t)(64 * bm + r) * 256 + k0 + ko];
        float4v v0 = src[0], v1 = src[1];
        short8v pk;
        pk[0] = f2bf(v0[0]); pk[1] = f2bf(v0[1]); pk[2] = f2bf(v0[2]); pk[3] = f2bf(v0[3]);
        pk[4] = f2bf(v1[0]); pk[5] = f2bf(v1[1]); pk[6] = f2bf(v1[2]); pk[7] = f2bf(v1[3]);
        *(short8v*)&sA[r * 40 + ko] = pk;
        short8v bv = *(const short8v*)&WT[(size_t)(64 * bn + r) * 256 + k0 + ko];
        *(short8v*)&sB[r * 40 + ko] = bv;
        __syncthreads();

        short8v af = *(const short8v*)&sA[(16 * w + l16) * 40 + quad * 8];
#pragma unroll
        for (int c = 0; c < 4; c++) {
            short8v bf = *(const short8v*)&sB[(16 * c + l16) * 40 + quad * 8];
            acc[c] = __builtin_amdgcn_mfma_f32_16x16x32_bf16(af, bf, acc[c], 0, 0, 0);
        }
        __syncthreads();
    }
#pragma unroll
    for (int c = 0; c < 4; c++)
#pragma unroll
        for (int j = 0; j < 4; j++) {
            int row = 64 * bm + 16 * w + quad * 4 + j;
            int col = 64 * bn + 16 * c + l16;
            Wh[(size_t)row * 256 + col] = acc[c][j];
        }
}

// Wh1 = Wh@a1, Wh2 = Wh@a2, global max(Wh2) via encoded atomicMax. 4 rows/block (1/wave).
__global__ __launch_bounds__(256) void k_rowstats(const float* __restrict__ Wh, const float* __restrict__ a,
                                                  float* __restrict__ Wh1, float* __restrict__ Wh2,
                                                  unsigned* __restrict__ maxenc) {
    int w = threadIdx.x >> 6, lane = threadIdx.x & 63;
    int row = blockIdx.x * 4 + w;
    float s1 = 0.f, s2 = 0.f;
#pragma unroll
    for (int j = 0; j < 4; j++) {
        int c = lane + 64 * j;
        float v = Wh[(size_t)row * 256 + c];
        s1 += v * a[c];
        s2 += v * a[256 + c];
    }
#pragma unroll
    for (int off = 32; off; off >>= 1) {
        s1 += __shfl_down(s1, off);
        s2 += __shfl_down(s2, off);
    }
    if (lane == 0) {
        Wh1[row] = s1;
        Wh2[row] = s2;
        unsigned u = __float_as_uint(s2);
        unsigned key = (u & 0x80000000u) ? ~u : (u | 0x80000000u);
        atomicMax(maxenc, key);
    }
}

// WhT[n][k] bf16 from Wh[k][n] fp32, 64x64 LDS tile
__global__ __launch_bounds__(256) void k_transpose(const float* __restrict__ Wh, short* __restrict__ WhT) {
    __shared__ short sT[64 * 72];
    int bm = blockIdx.x, bn = blockIdx.y;
    int t = threadIdx.x;
#pragma unroll
    for (int i = 0; i < 4; i++) {
        int idx = i * 256 + t;
        int r = idx >> 4, c4 = (idx & 15) * 4;
        float4v v = *(const float4v*)&Wh[(size_t)(64 * bm + r) * 256 + 64 * bn + c4];
#pragma unroll
        for (int j = 0; j < 4; j++) sT[(c4 + j) * 72 + r] = f2bf(v[j]);
    }
    __syncthreads();
    int c = t >> 2, ro = (t & 3) * 16;
#pragma unroll
    for (int hh = 0; hh < 2; hh++) {
        short8v v = *(const short8v*)&sT[c * 72 + ro + 8 * hh];
        *(short8v*)&WhT[(size_t)(64 * bn + c) * 8192 + 64 * bm + ro + 8 * hh] = v;
    }
}

// Fused masked-softmax GEMM, K-split. Grid (128, S). Block: M=64 rows, K slice Ksub, N=256.
// 512 threads / 8 waves; wave tile 32x64 (acc[2][4]).
// T14 reg-staged pipeline (named scalars, no address-taken arrays). Per stage:
//   issue adj/w2(k+1) + B(k+2) global loads        (>= 1 full stage of slack, counted waits)
//   ds_write B(k+1) regs -> sB[cur^1]              (compiler inserts counted vmcnt wait)
//   P-compute(k) -> sA
//   lgkmcnt(0); s_barrier                          (global loads stay in flight)
//   MFMA reads sA + sB[cur]; s_barrier
// Zero vmcnt(0) in the main loop.
// launch_bounds (512, 2): hipcc interprets arg2 as min BLOCKS/CU (measured: (512,4) forced a
// 64-VGPR cap = 8 waves/SIMD and spilled ~50 regs -> 412MB scratch traffic, r3/r4).
// (512,2) -> 16 waves/CU -> 128-VGPR budget; kernel needs ~116. LDS 73KB caps residency at
// 2 blocks/CU anyway, so declared occupancy is unchanged.
__global__ __launch_bounds__(512, 2) void k_gat(const float* __restrict__ adj, const short* __restrict__ WhT,
                                                const float* __restrict__ Wh1, const float* __restrict__ Wh2,
                                                const unsigned* __restrict__ maxenc,
                                                float* __restrict__ Cacc, float* __restrict__ Lacc,
                                                int Ksub) {
    __shared__ short sB[2][256 * 64]; // unpadded: row n = 64 shorts (128B), chunk-XOR swizzled
    __shared__ short sA[64 * 72];     // padded stride 72 shorts (144B = 9*16B -> conflict-free b128)
    int bm = blockIdx.x;              // 0..127 (64 rows each)
    int sidx = blockIdx.y;
    int kb = sidx * Ksub;
    int t = threadIdx.x;
    int lane = t & 63, quad = lane >> 4, l16 = lane & 15;
    int w = t >> 6;                   // 0..7
    int mr = (w >> 2) * 32;           // wave row offset: 0 or 32
    int cg = w & 3;                   // col-group 0..3 (64 cols each)

    // decode global max(Wh2)
    unsigned key = maxenc[0];
    unsigned u = (key & 0x80000000u) ? (key & 0x7fffffffu) : ~key;
    float maxw2 = __uint_as_float(u);

    // ---- P staging mapping: 8 threads per row
    int r  = t >> 3;          // staging row 0..63
    int kc = (t & 7) * 8;     // staging k offset 0..56
    float wh1r = Wh1[64 * bm + r];
    float sup = wh1r + maxw2;
    float ci = fmaxf(sup, 0.2f * sup);   // leaky_relu monotone => e_ij <= ci for all j

    const float* adj_row = &adj[(size_t)(64 * bm + r) * 8192 + kb];
    const float* w2base  = &Wh2[kb];

    // ---- B staging mapping: thread t owns row n = t>>1, half = t&1 (4 x b128 per stage)
    int nrow = t >> 1;
    int half = t & 1;
    const short* gB = &WhT[(size_t)nrow * 8192 + kb + half * 32];
    int nx = nrow & 7;
    // precomputed swizzled LDS write offsets (shorts)
    int sbw0 = nrow * 64 + (((half * 4 + 0) ^ nx)) * 8;
    int sbw1 = nrow * 64 + (((half * 4 + 1) ^ nx)) * 8;
    int sbw2 = nrow * 64 + (((half * 4 + 2) ^ nx)) * 8;
    int sbw3 = nrow * 64 + (((half * 4 + 3) ^ nx)) * 8;

    float4v acc[2][4];
#pragma unroll
    for (int rt = 0; rt < 2; rt++)
#pragma unroll
        for (int c = 0; c < 4; c++)
#pragma unroll
            for (int j = 0; j < 4; j++) acc[rt][c][j] = 0.f;
    float lsum = 0.f;

    // pipeline state: named scalars only
    short8v a0, a1, a2, a3;       // B ping
    short8v b0, b1, b2, b3;       // B pong
    float4v av0, av1, w20, w21;   // adj/w2 ping
    float4v cv0, cv1, x20, x21;   // adj/w2 pong

    // ---- prologue: adj/w2(0); B(0) -> write sB[0]; issue B(64)
    av0 = *(const float4v*)&adj_row[kc];
    av1 = *(const float4v*)&adj_row[kc + 4];
    w20 = *(const float4v*)&w2base[kc];
    w21 = *(const float4v*)&w2base[kc + 4];
    a0 = *(const short8v*)&gB[0];
    a1 = *(const short8v*)&gB[8];
    a2 = *(const short8v*)&gB[16];
    a3 = *(const short8v*)&gB[24];
    *(short8v*)&sB[0][sbw0] = a0;
    *(short8v*)&sB[0][sbw1] = a1;
    *(short8v*)&sB[0][sbw2] = a2;
    *(short8v*)&sB[0][sbw3] = a3;
    b0 = *(const short8v*)&gB[64];
    b1 = *(const short8v*)&gB[64 + 8];
    b2 = *(const short8v*)&gB[64 + 16];
    b3 = *(const short8v*)&gB[64 + 24];

// One pipeline stage. C0..C3 = B(k0+64) regs (write into sB[CUR^1]); N0..N3 receive B(k0+128).
// AV*/AW* = current adj/w2; NV*/NW* receive next.
#define STAGE(K0, CUR, C0, C1, C2, C3, N0, N1, N2, N3, AV0, AV1, AW0, AW1, NV0, NV1, NW0, NW1)   \
    {                                                                                            \
        int k1 = (K0) + 64, k2 = (K0) + 128;                                                     \
        if (k1 < Ksub) {                                                                         \
            NV0 = *(const float4v*)&adj_row[k1 + kc];                                            \
            NV1 = *(const float4v*)&adj_row[k1 + kc + 4];                                        \
            NW0 = *(const float4v*)&w2base[k1 + kc];                                             \
            NW1 = *(const float4v*)&w2base[k1 + kc + 4];                                         \
        }                                                                                        \
        if (k2 < Ksub) {                                                                         \
            N0 = *(const short8v*)&gB[k2];                                                       \
            N1 = *(const short8v*)&gB[k2 + 8];                                                   \
            N2 = *(const short8v*)&gB[k2 + 16];                                                  \
            N3 = *(const short8v*)&gB[k2 + 24];                                                  \
        }                                                                                        \
        if (k1 < Ksub) {                                                                         \
            *(short8v*)&sB[(CUR) ^ 1][sbw0] = C0;                                                \
            *(short8v*)&sB[(CUR) ^ 1][sbw1] = C1;                                                \
            *(short8v*)&sB[(CUR) ^ 1][sbw2] = C2;                                                \
            *(short8v*)&sB[(CUR) ^ 1][sbw3] = C3;                                                \
        }                                                                                        \
        short8v pk;                                                                              \
        _Pragma("unroll")                                                                        \
        for (int j = 0; j < 4; j++) {                                                            \
            float s = wh1r + AW0[j];                                                             \
            float f = fmaxf(s, 0.2f * s);                                                        \
            float p = __expf(f - ci);                                                            \
            p = (AV0[j] > 0.f) ? p : 0.f;                                                        \
            lsum += p;                                                                           \
            pk[j] = f2bf(p);                                                                     \
        }                                                                                        \
        _Pragma("unroll")                                                                        \
        for (int j = 0; j < 4; j++) {                                                            \
            float s = wh1r + AW1[j];                                                             \
            float f = fmaxf(s, 0.2f * s);                                                        \
            float p = __expf(f - ci);                                                            \
            p = (AV1[j] > 0.f) ? p : 0.f;                                                        \
            lsum += p;                                                                           \
            pk[4 + j] = f2bf(p);                                                                 \
        }                                                                                        \
        *(short8v*)&sA[r * 72 + kc] = pk;                                                        \
        asm volatile("s_waitcnt lgkmcnt(0)" ::: "memory");                                       \
        __builtin_amdgcn_s_barrier();                                                            \
        __builtin_amdgcn_s_setprio(1);                                                           \
        {                                                                                        \
            const short* sBc = &sB[(CUR)][0];                                                    \
            _Pragma("unroll")                                                                    \
            for (int kk = 0; kk < 2; kk++) {                                                     \
                short8v af0 = *(const short8v*)&sA[(mr + l16) * 72 + kk * 32 + quad * 8];        \
                short8v af1 = *(const short8v*)&sA[(mr + 16 + l16) * 72 + kk * 32 + quad * 8];   \
                _Pragma("unroll")                                                                \
                for (int c = 0; c < 4; c++) {                                                    \
                    int n = 64 * cg + 16 * c + l16;                                              \
                    int ch = (kk * 4 + quad) ^ (n & 7);                                          \
                    short8v bf = *(const short8v*)&sBc[n * 64 + ch * 8];                         \
                    acc[0][c] = __builtin_amdgcn_mfma_f32_16x16x32_bf16(af0, bf, acc[0][c], 0, 0, 0); \
                    acc[1][c] = __builtin_amdgcn_mfma_f32_16x16x32_bf16(af1, bf, acc[1][c], 0, 0, 0); \
                }                                                                                \
            }                                                                                    \
        }                                                                                        \
        __builtin_amdgcn_s_setprio(0);                                                           \
        __builtin_amdgcn_s_barrier();                                                            \
    }

    for (int k0 = 0; k0 < Ksub; k0 += 128) {
        STAGE(k0,      0, b0, b1, b2, b3, a0, a1, a2, a3, av0, av1, w20, w21, cv0, cv1, x20, x21)
        STAGE(k0 + 64, 1, a0, a1, a2, a3, b0, b1, b2, b3, cv0, cv1, x20, x21, av0, av1, w20, w21)
    }
#undef STAGE

    // reduce lsum across the 8 staging threads that share a row, then accumulate
#pragma unroll
    for (int off = 4; off; off >>= 1) lsum += __shfl_xor(lsum, off, 8);
    if ((t & 7) == 0) atomicAdd(&Lacc[64 * bm + r], lsum);

#pragma unroll
    for (int rt = 0; rt < 2; rt++)
#pragma unroll
        for (int c = 0; c < 4; c++)
#pragma unroll
            for (int j = 0; j < 4; j++) {
                int row = 64 * bm + mr + rt * 16 + quad * 4 + j;
                int col = 64 * cg + 16 * c + l16;
                atomicAdd(&Cacc[(size_t)row * 256 + col], acc[rt][c][j]);
            }
}

// out = elu( Cacc / Lacc )
__global__ __launch_bounds__(256) void k_final(const float* __restrict__ Cacc, const float* __restrict__ Lacc,
                                               float* __restrict__ out) {
    int idx = blockIdx.x * 256 + threadIdx.x;     // one float4 per thread; 2048 blocks
    int row = idx >> 6;
    int c4 = (idx & 63) * 4;
    float4v v = *(const float4v*)&Cacc[(size_t)row * 256 + c4];
    float inv = 1.0f / fmaxf(Lacc[row], 1e-30f);
    float4v o;
#pragma unroll
    for (int j = 0; j < 4; j++) {
        float x = v[j] * inv;
        o[j] = (x > 0.f) ? x : (__expf(x) - 1.f);
    }
    *(float4v*)&out[(size_t)row * 256 + c4] = o;
}

extern "C" void kernel_launch(void* const* d_in, const int* in_sizes, int n_in,
                              void* d_out, int out_size, void* d_ws, size_t ws_size,
                              hipStream_t stream) {
    const float* h   = (const float*)d_in[0];
    const float* adj = (const float*)d_in[1];
    const float* W   = (const float*)d_in[2];
    const float* a   = (const float*)d_in[3];
    float* out = (float*)d_out;

    const int S = 4;
    const int Ksub = NN / S;

    // ws layout (12.8 MB):
    //  [0, 8MB)      Wh (fp32)  — dead after k_rowstats/k_transpose, then ALIASED as Cacc
    //  [8MB, 12MB)   WhT (bf16)
    //  tail: WT 128KB | Wh1 32KB | Wh2 32KB | Lacc 32KB | maxenc 4B
    char* ws = (char*)d_ws;
    float*    Wh     = (float*)(ws);
    float*    Cacc   = (float*)(ws);                 // alias of Wh (stream-ordered safe)
    short*    WhT    = (short*)(ws + 8388608);
    char*     tail   = ws + 12582912;
    short*    WT     = (short*)(tail);
    float*    Wh1    = (float*)(tail + 131072);
    float*    Wh2    = (float*)(tail + 163840);
    float*    Lacc   = (float*)(tail + 196608);
    unsigned* maxenc = (unsigned*)(tail + 229376);

    hipMemsetAsync(maxenc, 0, sizeof(unsigned), stream);

    k_wt<<<256, 256, 0, stream>>>(W, WT);
    k_gemm1<<<dim3(128, 4), 256, 0, stream>>>(h, WT, Wh);
    k_rowstats<<<2048, 256, 0, stream>>>(Wh, a, Wh1, Wh2, maxenc);
    k_transpose<<<dim3(128, 4), 256, 0, stream>>>(Wh, WhT);
    // Wh is dead now; zero it for use as Cacc, zero Lacc
    hipMemsetAsync(Cacc, 0, (size_t)NN * 256 * sizeof(float), stream);
    hipMemsetAsync(Lacc, 0, (size_t)NN * sizeof(float), stream);
    k_gat<<<dim3(128, S), 512, 0, stream>>>(adj, WhT, Wh1, Wh2, maxenc, Cacc, Lacc, Ksub);
    k_final<<<2048, 256, 0, stream>>>(Cacc, Lacc, out);
}